// Round 6
// baseline (1641.026 us; speedup 1.0000x reference)
//
#include <hip/hip_runtime.h>
#include <stdint.h>

#define BB 64      // batch
#define TT 64      // time steps
#define NIN 128
#define NHID 256
#define NOUT 32
#define BPS 4                  // blocks per sample (j-sliced)
#define NBLK (BB * BPS)        // 256 = one block per CU
#define NTHR 1024
#define JS 64                  // j-columns per block

#define SIG_NEU 0.05f
#define SIG_SYN 0.002f

// workspace layout (bytes)
#define FLAG_OFF    0
#define FLAG_STRIDE 32                                // u32s -> 128B per flag line
#define FLAG_BYTES  (BB * BPS * FLAG_STRIDE * 4)      // 32 KB, memset(0) per launch
#define HPUB_OFF    FLAG_BYTES                        // float[2][BB][NHID] = 128 KB

#define HID_LIST_SZ ((size_t)BB * TT * NHID)          // 1048576
#define OUT_LIST_SZ ((size_t)BB * TT * NOUT)          // 131072

__device__ __forceinline__ uint32_t rotl32(uint32_t v, int s) {
  return (v << s) | (v >> (32 - s));
}

// JAX threefry2x32 (5 groups of 4 rounds)
__device__ __forceinline__ void tf2x32(uint32_t k0, uint32_t k1, uint32_t x0, uint32_t x1,
                                       uint32_t& o0, uint32_t& o1) {
  const uint32_t k2 = k0 ^ k1 ^ 0x1BD11BDAu;
  x0 += k0; x1 += k1;
  x0 += x1; x1 = rotl32(x1,13); x1 ^= x0;
  x0 += x1; x1 = rotl32(x1,15); x1 ^= x0;
  x0 += x1; x1 = rotl32(x1,26); x1 ^= x0;
  x0 += x1; x1 = rotl32(x1, 6); x1 ^= x0;
  x0 += k1; x1 += k2 + 1u;
  x0 += x1; x1 = rotl32(x1,17); x1 ^= x0;
  x0 += x1; x1 = rotl32(x1,29); x1 ^= x0;
  x0 += x1; x1 = rotl32(x1,16); x1 ^= x0;
  x0 += x1; x1 = rotl32(x1,24); x1 ^= x0;
  x0 += k2; x1 += k0 + 2u;
  x0 += x1; x1 = rotl32(x1,13); x1 ^= x0;
  x0 += x1; x1 = rotl32(x1,15); x1 ^= x0;
  x0 += x1; x1 = rotl32(x1,26); x1 ^= x0;
  x0 += x1; x1 = rotl32(x1, 6); x1 ^= x0;
  x0 += k0; x1 += k1 + 3u;
  x0 += x1; x1 = rotl32(x1,17); x1 ^= x0;
  x0 += x1; x1 = rotl32(x1,29); x1 ^= x0;
  x0 += x1; x1 = rotl32(x1,16); x1 ^= x0;
  x0 += x1; x1 = rotl32(x1,24); x1 ^= x0;
  x0 += k1; x1 += k2 + 4u;
  x0 += x1; x1 = rotl32(x1,13); x1 ^= x0;
  x0 += x1; x1 = rotl32(x1,15); x1 ^= x0;
  x0 += x1; x1 = rotl32(x1,26); x1 ^= x0;
  x0 += x1; x1 = rotl32(x1, 6); x1 ^= x0;
  x0 += k2; x1 += k0 + 5u;
  o0 = x0; o1 = x1;
}

// partitionable random_bits(32) element idx -> N(0,1) exactly as jax.random.normal
__device__ __forceinline__ float tf_normal(uint32_t k0, uint32_t k1, uint32_t idx) {
  uint32_t o0, o1;
  tf2x32(k0, k1, 0u, idx, o0, o1);
  const uint32_t bits = o0 ^ o1;
  const float u = __uint_as_float((bits >> 9) | 0x3f800000u) - 1.0f;  // [0,1)
  float x = fmaf(u, 2.0f, -0.99999994f);                              // [-1+eps, 1)
  x = fmaxf(x, -0.99999994f);
  // XLA ErfInv f32 (Giles)
  const float w = -__logf(fmaf(-x, x, 1.0f));
  float p;
  if (w < 5.0f) {
    const float q = w - 2.5f;
    p = 2.81022636e-08f;
    p = fmaf(p, q, 3.43273939e-07f);
    p = fmaf(p, q, -3.5233877e-06f);
    p = fmaf(p, q, -4.39150654e-06f);
    p = fmaf(p, q, 0.00021858087f);
    p = fmaf(p, q, -0.00125372503f);
    p = fmaf(p, q, -0.00417768164f);
    p = fmaf(p, q, 0.246640727f);
    p = fmaf(p, q, 1.50140941f);
  } else {
    const float q = sqrtf(w) - 3.0f;
    p = -0.000200214257f;
    p = fmaf(p, q, 0.000100950558f);
    p = fmaf(p, q, 0.00134934322f);
    p = fmaf(p, q, -0.00367342844f);
    p = fmaf(p, q, 0.00573950773f);
    p = fmaf(p, q, -0.0076224613f);
    p = fmaf(p, q, 0.00943887047f);
    p = fmaf(p, q, 1.00167406f);
    p = fmaf(p, q, 2.83297682f);
  }
  return 1.41421356f * (p * x);  // sqrt(2)*erfinv
}

#define SPIN(slice, want)                                                         \
  do {                                                                            \
    uint32_t* fp_ = &flags[((b) * BPS + (slice)) * FLAG_STRIDE];                  \
    for (int it_ = 0; it_ < 2000000; ++it_) {                                     \
      if (__hip_atomic_load(fp_, __ATOMIC_RELAXED, __HIP_MEMORY_SCOPE_AGENT) >=   \
          (uint32_t)(want)) break;                                                \
      __builtin_amdgcn_s_sleep(1);                                                \
    }                                                                             \
  } while (0)

__global__ __launch_bounds__(NTHR)
__attribute__((amdgpu_waves_per_eu(4, 4)))   // pin 4 waves/EU: full 128-VGPR budget, no spill
void rnn_kernel(
    const float* __restrict__ xin, const float* __restrict__ h0,
    const float* __restrict__ w_in, const float* __restrict__ w_hh,
    const float* __restrict__ b_hh, const float* __restrict__ w_out,
    const float* __restrict__ alpha, const float* __restrict__ beta,
    float* __restrict__ out, char* __restrict__ ws)
{
  __shared__ __align__(16) float wos[8 * 260];   // w_out slice (8 rows), +4 pad
  __shared__ __align__(16) float h_s[NHID];
  __shared__ __align__(16) float a_s[NHID];
  __shared__ __align__(16) float xt_s[NIN];
  __shared__ float stat_s[JS];
  __shared__ float djact_s[JS];
  __shared__ uint32_t keys_s[TT * 4];

  const int tid = threadIdx.x;
  const int blk = blockIdx.x;
  const int b   = blk & 63;      // sample; siblings blk = s*64+b are == b (mod 8) -> same XCD
  const int s   = blk >> 6;      // 0..3 j-slice index

  uint32_t* flags = (uint32_t*)(ws + FLAG_OFF);
  float*    hpub  = (float*)(ws + HPUB_OFF);

  // ---------------- init ----------------
  if (tid < TT) {
    uint32_t ka, kb, t0, t1;
    tf2x32(0u, 42u, 0u, (uint32_t)tid, ka, kb);   // keys[t] = split(key(42),64)[t]
    tf2x32(ka, kb, 0u, 0u, t0, t1);               // k1 (neural)
    keys_s[tid * 4 + 0] = t0; keys_s[tid * 4 + 1] = t1;
    tf2x32(ka, kb, 0u, 1u, t0, t1);               // k2 (synaptic)
    keys_s[tid * 4 + 2] = t0; keys_s[tid * 4 + 3] = t1;
  }
  if (tid < NHID) {
    const float hv = h0[b * NHID + tid];
    h_s[tid] = hv;
    a_s[tid] = tanhf(hv);
  }
  #pragma unroll
  for (int e = 0; e < 2; ++e) {                   // w_out slice -> LDS
    const int idx = tid + e * NTHR;
    const int r = idx >> 8, c = idx & 255;
    wos[r * 260 + c] = w_out[(s * 8 + r) * NHID + c];
  }

  // thread mapping: jl = dj column / GEMV row (0..63), q = 16-lane slice (0..15)
  // this thread owns dj rows i in [16q, 16q+16) for column jg
  const int q  = tid & 15;
  const int jl = tid >> 4;           // 0..63
  const int jg = s * JS + jl;        // global j / GEMV row
  const int rot2 = q >> 2;           // chunk rotation for 16-float slices
  const int rot1 = q >> 3;           // chunk rotation for 8-float slices
  const float bj  = beta[jg];
  const float sbj = SIG_SYN * sqrtf(bj);
  const uint32_t idxb = ((uint32_t)b << 16) | ((uint32_t)(q * 16) << 8) | (uint32_t)jg;

  // loop-invariant GEMV weights in registers, pre-rotated chunk order (24 VGPR)
  float4 whr[4], winr[2];
  #pragma unroll
  for (int k = 0; k < 4; ++k)
    whr[k] = *(const float4*)(w_hh + (size_t)jg * NHID + q * 16 + ((k + rot2) & 3) * 4);
  #pragma unroll
  for (int k = 0; k < 2; ++k)
    winr[k] = *(const float4*)(w_in + (size_t)jg * NIN + q * 8 + ((k + rot1) & 1) * 4);
  const float bias = b_hh[jg];

  // h-update consts (tid<64)
  float r_al = 0.f, r_om = 0.f, r_ns = 0.f;
  uint32_t hnidx = 0;
  if (tid < JS) {
    r_al = alpha[s * JS + tid];
    r_om = 1.0f - r_al;
    r_ns = SIG_NEU * sqrtf(r_al);
    hnidx = (uint32_t)(b * NHID + s * JS + tid);
  }

  float d[16];
  #pragma unroll
  for (int r = 0; r < 16; ++r) d[r] = 0.0f;
  float n[16];
  float hn = 0.0f;

  __syncthreads();

  // -------- prologue: RNG for t=0, x_0 --------
  {
    const uint32_t k2a = __builtin_amdgcn_readfirstlane(keys_s[2]);
    const uint32_t k2b = __builtin_amdgcn_readfirstlane(keys_s[3]);
    #pragma unroll
    for (int kk = 0; kk < 4; ++kk) {
      const int chunk = (kk + rot2) & 3;
      #pragma unroll
      for (int c = 0; c < 4; ++c)
        n[kk * 4 + c] = tf_normal(k2a, k2b, idxb + ((uint32_t)(chunk * 4 + c) << 8));
    }
    if (tid < JS) {
      const uint32_t k1a = __builtin_amdgcn_readfirstlane(keys_s[0]);
      const uint32_t k1b = __builtin_amdgcn_readfirstlane(keys_s[1]);
      hn = tf_normal(k1a, k1b, hnidx);
    }
    if (tid < NIN) xt_s[tid] = xin[((size_t)b * TT) * NIN + tid];
  }
  __syncthreads();

  const int wv = tid >> 6;     // wave id 0..15
  const int ln = tid & 63;

  for (int t = 0; t < TT; ++t) {
    const int par = t & 1;

    // ================ P1: dj + GEMV + outproj(t-1) ================
    const float aj = a_s[jg];
    float pd = 0.0f;
    float acc = 0.0f;
    #pragma unroll
    for (int kk = 0; kk < 4; ++kk) {
      const int chunk = (kk + rot2) & 3;
      const float4 av = *(const float4*)(a_s + q * 16 + chunk * 4);  // rotated: 2-way banks
      // dj rows i = 16q + chunk*4 + c
      pd = fmaf(av.x, d[kk*4+0], pd);
      pd = fmaf(av.y, d[kk*4+1], pd);
      pd = fmaf(av.z, d[kk*4+2], pd);
      pd = fmaf(av.w, d[kk*4+3], pd);
      d[kk*4+0] = fmaf(bj, fmaf(n[kk*4+0], sbj, -av.x * aj), d[kk*4+0]);
      d[kk*4+1] = fmaf(bj, fmaf(n[kk*4+1], sbj, -av.y * aj), d[kk*4+1]);
      d[kk*4+2] = fmaf(bj, fmaf(n[kk*4+2], sbj, -av.z * aj), d[kk*4+2]);
      d[kk*4+3] = fmaf(bj, fmaf(n[kk*4+3], sbj, -av.w * aj), d[kk*4+3]);
      // GEMV hh part reuses the same av
      acc = fmaf(whr[kk].x, av.x, acc); acc = fmaf(whr[kk].y, av.y, acc);
      acc = fmaf(whr[kk].z, av.z, acc); acc = fmaf(whr[kk].w, av.w, acc);
    }
    #pragma unroll
    for (int k = 0; k < 2; ++k) {
      const int chunk = (k + rot1) & 1;
      const float4 xv = *(const float4*)(xt_s + q * 8 + chunk * 4);
      acc = fmaf(winr[k].x, xv.x, acc); acc = fmaf(winr[k].y, xv.y, acc);
      acc = fmaf(winr[k].z, xv.z, acc); acc = fmaf(winr[k].w, xv.w, acc);
    }
    pd += __shfl_xor(pd, 1);
    pd += __shfl_xor(pd, 2);
    pd += __shfl_xor(pd, 4);
    pd += __shfl_xor(pd, 8);
    acc += __shfl_xor(acc, 1);
    acc += __shfl_xor(acc, 2);
    acc += __shfl_xor(acc, 4);
    acc += __shfl_xor(acc, 8);
    if (q == 0) {
      djact_s[jl] = pd;
      stat_s[jl]  = acc + bias;
    }

    if (wv == 15 && t > 0) {   // output projection for t-1 (h_s = h(t-1)); 8 outputs
      const int o = ln >> 3, sub = ln & 7;
      float oacc = 0.0f;
      #pragma unroll
      for (int k = 0; k < 8; ++k) {
        const int ck = (k + sub) & 7;  // rotate to spread banks
        const float4 wvv = *(const float4*)(wos + o * 260 + sub * 32 + ck * 4);
        const float4 hv  = *(const float4*)(h_s + sub * 32 + ck * 4);
        oacc = fmaf(wvv.x, hv.x, oacc); oacc = fmaf(wvv.y, hv.y, oacc);
        oacc = fmaf(wvv.z, hv.z, oacc); oacc = fmaf(wvv.w, hv.w, oacc);
      }
      oacc += __shfl_xor(oacc, 1);
      oacc += __shfl_xor(oacc, 2);
      oacc += __shfl_xor(oacc, 4);
      if (sub == 0)
        out[HID_LIST_SZ + ((size_t)b * TT + (t - 1)) * NOUT + s * 8 + o] =
            20.0f * tanhf(oacc);
    }
    __syncthreads();

    // ================ P2: h-update + publish, then RNG(t+1) ================
    if (tid < JS) {
      const float tmp  = stat_s[tid] + djact_s[tid];
      const float hnew = fmaf(r_al, tmp, r_om * h_s[s * JS + tid]) + hn * r_ns;
      __hip_atomic_store(&hpub[(par * BB + b) * NHID + s * JS + tid], hnew,
                         __ATOMIC_RELAXED, __HIP_MEMORY_SCOPE_AGENT);
    }
    if (tid == 0) {
      asm volatile("s_waitcnt vmcnt(0)" ::: "memory");   // h-slice visible first
      __hip_atomic_store(&flags[(b * BPS + s) * FLAG_STRIDE], (uint32_t)(t + 1),
                         __ATOMIC_RELAXED, __HIP_MEMORY_SCOPE_AGENT);
    }
    if (t + 1 < TT) {   // RNG for next step — hides the publish/flag latency
      const uint32_t k2a = __builtin_amdgcn_readfirstlane(keys_s[(t + 1) * 4 + 2]);
      const uint32_t k2b = __builtin_amdgcn_readfirstlane(keys_s[(t + 1) * 4 + 3]);
      #pragma unroll
      for (int kk = 0; kk < 4; ++kk) {
        const int chunk = (kk + rot2) & 3;
        #pragma unroll
        for (int c = 0; c < 4; ++c)
          n[kk * 4 + c] = tf_normal(k2a, k2b, idxb + ((uint32_t)(chunk * 4 + c) << 8));
      }
      if (tid < JS) {
        const uint32_t k1a = __builtin_amdgcn_readfirstlane(keys_s[(t + 1) * 4 + 0]);
        const uint32_t k1b = __builtin_amdgcn_readfirstlane(keys_s[(t + 1) * 4 + 1]);
        hn = tf_normal(k1a, k1b, hnidx);
      }
    }

    // ================ P3: poll flags, pull h(t), side jobs ================
    if (wv < 4) {
      if (ln == 0) SPIN(wv, t + 1);
      asm volatile("" ::: "memory");
      const float hv = __hip_atomic_load(&hpub[(par * BB + b) * NHID + wv * JS + ln],
                                         __ATOMIC_RELAXED, __HIP_MEMORY_SCOPE_AGENT);
      h_s[wv * JS + ln] = hv;
      a_s[wv * JS + ln] = tanhf(hv);
    } else if (wv < 8) {
      if (s == 0) {   // hidden_list (deduped: only s==0 writes)
        const int sl = wv - 4;
        const int k  = sl * JS + ln;
        if (ln == 0) SPIN(sl, t + 1);
        asm volatile("" ::: "memory");
        const float hv = __hip_atomic_load(&hpub[(par * BB + b) * NHID + k],
                                           __ATOMIC_RELAXED, __HIP_MEMORY_SCOPE_AGENT);
        out[((size_t)b * TT + t) * NHID + k] = hv;
        if (t == TT - 1)
          out[HID_LIST_SZ + OUT_LIST_SZ + (size_t)b * NHID + k] = hv;
      }
    } else if (wv < 10) {
      const int k = (wv - 8) * 64 + ln;            // 0..127: x prefetch
      if (t + 1 < TT) xt_s[k] = xin[((size_t)b * TT + t + 1) * NIN + k];
    }
    __syncthreads();
  }

  // ---- epilogue: output projection for t = 63 (h_s = h(63)) ----
  if (wv == 15) {
    const int o = ln >> 3, sub = ln & 7;
    float oacc = 0.0f;
    #pragma unroll
    for (int k = 0; k < 8; ++k) {
      const int ck = (k + sub) & 7;
      const float4 wvv = *(const float4*)(wos + o * 260 + sub * 32 + ck * 4);
      const float4 hv  = *(const float4*)(h_s + sub * 32 + ck * 4);
      oacc = fmaf(wvv.x, hv.x, oacc); oacc = fmaf(wvv.y, hv.y, oacc);
      oacc = fmaf(wvv.z, hv.z, oacc); oacc = fmaf(wvv.w, hv.w, oacc);
    }
    oacc += __shfl_xor(oacc, 1);
    oacc += __shfl_xor(oacc, 2);
    oacc += __shfl_xor(oacc, 4);
    if (sub == 0)
      out[HID_LIST_SZ + ((size_t)b * TT + (TT - 1)) * NOUT + s * 8 + o] =
          20.0f * tanhf(oacc);
  }
}

extern "C" void kernel_launch(void* const* d_in, const int* in_sizes, int n_in,
                              void* d_out, int out_size, void* d_ws, size_t ws_size,
                              hipStream_t stream) {
  (void)in_sizes; (void)n_in; (void)out_size; (void)ws_size;
  const float* x     = (const float*)d_in[0];
  const float* h0    = (const float*)d_in[1];
  // d_in[2] = length (always 64)
  const float* w_in  = (const float*)d_in[3];
  const float* w_hh  = (const float*)d_in[4];
  const float* b_hh  = (const float*)d_in[5];
  const float* w_out = (const float*)d_in[6];
  const float* alpha = (const float*)d_in[7];
  const float* beta  = (const float*)d_in[8];
  float* out = (float*)d_out;

  hipMemsetAsync((char*)d_ws + FLAG_OFF, 0, FLAG_BYTES, stream);  // flag slots
  rnn_kernel<<<dim3(NBLK), dim3(NTHR), 0, stream>>>(
      x, h0, w_in, w_hh, b_hh, w_out, alpha, beta, out, (char*)d_ws);
}

// Round 8
// 894.734 us; speedup vs baseline: 1.8341x; 1.8341x over previous
//
#include <hip/hip_runtime.h>
#include <stdint.h>

#define BB 64      // batch
#define TT 64      // time steps
#define NIN 128
#define NHID 256
#define NOUT 32
#define BPS 8                  // blocks per sample (j-sliced)
#define NBLK (BB * BPS)        // 512 blocks = 2 per CU (LDS-limited, co-resident)
#define NTHR 256
#define JS 32                  // j-columns per block

#define SIG_NEU 0.05f
#define SIG_SYN 0.002f

// workspace layout (bytes)
#define FLAG_OFF    0
#define FLAG_STRIDE 32                                // u32s -> 128B per flag line
#define FLAG_BYTES  (BB * BPS * FLAG_STRIDE * 4)      // 64 KB, memset(0) per launch
#define HPUB_OFF    FLAG_BYTES                        // float[2][BB][NHID] = 128 KB

#define HID_LIST_SZ ((size_t)BB * TT * NHID)          // 1048576
#define OUT_LIST_SZ ((size_t)BB * TT * NOUT)          // 131072

__device__ __forceinline__ uint32_t rotl32(uint32_t v, int s) {
  return (v << s) | (v >> (32 - s));
}

// JAX threefry2x32 (5 groups of 4 rounds)
__device__ __forceinline__ void tf2x32(uint32_t k0, uint32_t k1, uint32_t x0, uint32_t x1,
                                       uint32_t& o0, uint32_t& o1) {
  const uint32_t k2 = k0 ^ k1 ^ 0x1BD11BDAu;
  x0 += k0; x1 += k1;
  x0 += x1; x1 = rotl32(x1,13); x1 ^= x0;
  x0 += x1; x1 = rotl32(x1,15); x1 ^= x0;
  x0 += x1; x1 = rotl32(x1,26); x1 ^= x0;
  x0 += x1; x1 = rotl32(x1, 6); x1 ^= x0;
  x0 += k1; x1 += k2 + 1u;
  x0 += x1; x1 = rotl32(x1,17); x1 ^= x0;
  x0 += x1; x1 = rotl32(x1,29); x1 ^= x0;
  x0 += x1; x1 = rotl32(x1,16); x1 ^= x0;
  x0 += x1; x1 = rotl32(x1,24); x1 ^= x0;
  x0 += k2; x1 += k0 + 2u;
  x0 += x1; x1 = rotl32(x1,13); x1 ^= x0;
  x0 += x1; x1 = rotl32(x1,15); x1 ^= x0;
  x0 += x1; x1 = rotl32(x1,26); x1 ^= x0;
  x0 += x1; x1 = rotl32(x1, 6); x1 ^= x0;
  x0 += k0; x1 += k1 + 3u;
  x0 += x1; x1 = rotl32(x1,17); x1 ^= x0;
  x0 += x1; x1 = rotl32(x1,29); x1 ^= x0;
  x0 += x1; x1 = rotl32(x1,16); x1 ^= x0;
  x0 += x1; x1 = rotl32(x1,24); x1 ^= x0;
  x0 += k1; x1 += k2 + 4u;
  x0 += x1; x1 = rotl32(x1,13); x1 ^= x0;
  x0 += x1; x1 = rotl32(x1,15); x1 ^= x0;
  x0 += x1; x1 = rotl32(x1,26); x1 ^= x0;
  x0 += x1; x1 = rotl32(x1, 6); x1 ^= x0;
  x0 += k2; x1 += k0 + 5u;
  o0 = x0; o1 = x1;
}

// partitionable random_bits(32) element idx -> N(0,1) exactly as jax.random.normal
__device__ __forceinline__ float tf_normal(uint32_t k0, uint32_t k1, uint32_t idx) {
  uint32_t o0, o1;
  tf2x32(k0, k1, 0u, idx, o0, o1);
  const uint32_t bits = o0 ^ o1;
  const float u = __uint_as_float((bits >> 9) | 0x3f800000u) - 1.0f;  // [0,1)
  float x = fmaf(u, 2.0f, -0.99999994f);                              // [-1+eps, 1)
  x = fmaxf(x, -0.99999994f);
  // XLA ErfInv f32 (Giles)
  const float w = -__logf(fmaf(-x, x, 1.0f));
  float p;
  if (w < 5.0f) {
    const float q = w - 2.5f;
    p = 2.81022636e-08f;
    p = fmaf(p, q, 3.43273939e-07f);
    p = fmaf(p, q, -3.5233877e-06f);
    p = fmaf(p, q, -4.39150654e-06f);
    p = fmaf(p, q, 0.00021858087f);
    p = fmaf(p, q, -0.00125372503f);
    p = fmaf(p, q, -0.00417768164f);
    p = fmaf(p, q, 0.246640727f);
    p = fmaf(p, q, 1.50140941f);
  } else {
    const float q = sqrtf(w) - 3.0f;
    p = -0.000200214257f;
    p = fmaf(p, q, 0.000100950558f);
    p = fmaf(p, q, 0.00134934322f);
    p = fmaf(p, q, -0.00367342844f);
    p = fmaf(p, q, 0.00573950773f);
    p = fmaf(p, q, -0.0076224613f);
    p = fmaf(p, q, 0.00943887047f);
    p = fmaf(p, q, 1.00167406f);
    p = fmaf(p, q, 2.83297682f);
  }
  return 1.41421356f * (p * x);  // sqrt(2)*erfinv
}

#define SPIN(slice, want)                                                         \
  do {                                                                            \
    uint32_t* fp_ = &flags[((b) * BPS + (slice)) * FLAG_STRIDE];                  \
    for (int it_ = 0; it_ < 2000000; ++it_) {                                     \
      if (__hip_atomic_load(fp_, __ATOMIC_RELAXED, __HIP_MEMORY_SCOPE_AGENT) >=   \
          (uint32_t)(want)) break;                                                \
      __builtin_amdgcn_s_sleep(1);                                                \
    }                                                                             \
  } while (0)

__global__ __launch_bounds__(NTHR)
__attribute__((amdgpu_waves_per_eu(2)))   // min 2 waves/EU: VGPR budget 256, no spill
void rnn_kernel(
    const float* __restrict__ xin, const float* __restrict__ h0,
    const float* __restrict__ w_in, const float* __restrict__ w_hh,
    const float* __restrict__ b_hh, const float* __restrict__ w_out,
    const float* __restrict__ alpha, const float* __restrict__ beta,
    float* __restrict__ out, char* __restrict__ ws)
{
  __shared__ __align__(16) float whh_s[JS * 260];   // 33.3 KB, pad 260
  __shared__ __align__(16) float win_s[JS * 132];   // 16.9 KB, pad 132
  __shared__ __align__(16) float wos[4 * 260];      //  4.2 KB
  __shared__ __align__(16) float h_s[NHID];
  __shared__ __align__(16) float a_s[NHID];
  __shared__ __align__(16) float xt_s[NIN];
  __shared__ float stat_s[JS];
  __shared__ float djact_s[JS];
  __shared__ uint32_t keys_s[TT * 4];

  const int tid = threadIdx.x;
  const int blk = blockIdx.x;
  const int b   = blk & 63;      // sample; siblings blk = s*64+b are == b (mod 8)
  const int s   = blk >> 6;      // 0..7 j-slice index

  uint32_t* flags = (uint32_t*)(ws + FLAG_OFF);
  float*    hpub  = (float*)(ws + HPUB_OFF);

  // ---------------- init ----------------
  if (tid < TT) {
    uint32_t ka, kb, t0, t1;
    tf2x32(0u, 42u, 0u, (uint32_t)tid, ka, kb);   // keys[t] = split(key(42),64)[t]
    tf2x32(ka, kb, 0u, 0u, t0, t1);               // k1 (neural)
    keys_s[tid * 4 + 0] = t0; keys_s[tid * 4 + 1] = t1;
    tf2x32(ka, kb, 0u, 1u, t0, t1);               // k2 (synaptic)
    keys_s[tid * 4 + 2] = t0; keys_s[tid * 4 + 3] = t1;
  }
  {
    const float hv = h0[b * NHID + tid];
    h_s[tid] = hv;
    a_s[tid] = tanhf(hv);
  }
  #pragma unroll
  for (int r = 0; r < JS; ++r)
    whh_s[r * 260 + tid] = w_hh[(size_t)(s * JS + r) * NHID + tid];
  {
    const int r2 = tid >> 7, c = tid & 127;
    #pragma unroll
    for (int rr = 0; rr < 16; ++rr)
      win_s[(rr * 2 + r2) * 132 + c] = w_in[(size_t)(s * JS + rr * 2 + r2) * NIN + c];
  }
  #pragma unroll
  for (int r = 0; r < 4; ++r)
    wos[r * 260 + tid] = w_out[(s * 4 + r) * NHID + tid];

  // mapping: jl = GEMV row / dj column (0..31), q = 8-lane slice (0..7)
  // thread owns dj rows i = q*32 + [0,32), rotated: d[c4*4+cc] <-> row q*32+((c4+q)&7)*4+cc
  const int q  = tid & 7;
  const int jl = tid >> 3;           // 0..31
  const int jg = s * JS + jl;        // global j (0..255)
  const float bj   = beta[jg];
  const float sbj  = SIG_SYN * sqrtf(bj);
  const float bjsb = bj * sbj;
  const uint32_t idx0 = ((uint32_t)b << 16) | (uint32_t)jg;
  const float bias = b_hh[jg];

  // h-update consts (tid<32)
  float r_al = 0.f, r_om = 0.f, r_ns = 0.f;
  uint32_t hnidx = 0;
  if (tid < JS) {
    r_al = alpha[s * JS + tid];
    r_om = 1.0f - r_al;
    r_ns = SIG_NEU * sqrtf(r_al);
    hnidx = (uint32_t)(b * NHID + s * JS + tid);
  }

  float d[32];
  #pragma unroll
  for (int r = 0; r < 32; ++r) d[r] = 0.0f;   // dj(0) = 0 EXACTLY (no prologue noise)
  float hn = 0.0f;

  __syncthreads();

  // -------- prologue: hn(0), x_0 (NO noise fold: dj(0)=0) --------
  {
    if (tid < JS) {
      const uint32_t k1a = __builtin_amdgcn_readfirstlane(keys_s[0]);
      const uint32_t k1b = __builtin_amdgcn_readfirstlane(keys_s[1]);
      hn = tf_normal(k1a, k1b, hnidx);
    }
    if (tid < NIN) xt_s[tid] = xin[((size_t)b * TT) * NIN + tid];
  }
  __syncthreads();

  const int wv = tid >> 6;     // wave id 0..3
  const int ln = tid & 63;

  for (int t = 0; t < TT; ++t) {
    const int par = t & 1;

    // ================ P1: pd + outer-update + GEMV (+outproj t-1 on wave 3) ===========
    // d == dj(t) exactly: noise(t-1) was folded during the previous barrier window.
    const float aj = a_s[jg];
    float pd = 0.0f;
    float acc = 0.0f;
    #pragma unroll
    for (int c4 = 0; c4 < 8; ++c4) {
      const int col = q * 32 + ((c4 + q) & 7) * 4;               // rotated chunk
      const float4 av = *(const float4*)(a_s + col);
      const float4 wv4 = *(const float4*)(whh_s + jl * 260 + col);
      pd = fmaf(av.x, d[c4*4+0], pd);
      pd = fmaf(av.y, d[c4*4+1], pd);
      pd = fmaf(av.z, d[c4*4+2], pd);
      pd = fmaf(av.w, d[c4*4+3], pd);
      d[c4*4+0] = fmaf(bj, -av.x * aj, d[c4*4+0]);
      d[c4*4+1] = fmaf(bj, -av.y * aj, d[c4*4+1]);
      d[c4*4+2] = fmaf(bj, -av.z * aj, d[c4*4+2]);
      d[c4*4+3] = fmaf(bj, -av.w * aj, d[c4*4+3]);
      acc = fmaf(wv4.x, av.x, acc); acc = fmaf(wv4.y, av.y, acc);
      acc = fmaf(wv4.z, av.z, acc); acc = fmaf(wv4.w, av.w, acc);
    }
    #pragma unroll
    for (int k = 0; k < 4; ++k) {
      const int col = q * 16 + ((k + q) & 3) * 4;
      const float4 xv = *(const float4*)(xt_s + col);
      const float4 wv4 = *(const float4*)(win_s + jl * 132 + col);
      acc = fmaf(wv4.x, xv.x, acc); acc = fmaf(wv4.y, xv.y, acc);
      acc = fmaf(wv4.z, xv.z, acc); acc = fmaf(wv4.w, xv.w, acc);
    }
    pd  += __shfl_xor(pd, 1);  pd  += __shfl_xor(pd, 2);  pd  += __shfl_xor(pd, 4);
    acc += __shfl_xor(acc, 1); acc += __shfl_xor(acc, 2); acc += __shfl_xor(acc, 4);
    if (q == 0) {
      djact_s[jl] = pd;
      stat_s[jl]  = acc + bias;
    }

    if (wv == 3 && t > 0) {   // output projection for t-1 (h_s = h(t)); 4 outputs
      const int o = ln >> 4, sub = ln & 15;
      float oacc = 0.0f;
      #pragma unroll
      for (int k = 0; k < 4; ++k) {
        const int col = sub * 16 + ((k + sub) & 3) * 4;
        const float4 wvv = *(const float4*)(wos + o * 260 + col);
        const float4 hv  = *(const float4*)(h_s + col);
        oacc = fmaf(wvv.x, hv.x, oacc); oacc = fmaf(wvv.y, hv.y, oacc);
        oacc = fmaf(wvv.z, hv.z, oacc); oacc = fmaf(wvv.w, hv.w, oacc);
      }
      oacc += __shfl_xor(oacc, 1); oacc += __shfl_xor(oacc, 2);
      oacc += __shfl_xor(oacc, 4); oacc += __shfl_xor(oacc, 8);
      if (sub == 0)
        out[HID_LIST_SZ + ((size_t)b * TT + (t - 1)) * NOUT + s * 4 + o] =
            20.0f * tanhf(oacc);
    }
    __syncthreads();

    // ================ P2: h-update + publish + flag ================
    if (tid < JS) {
      const float tmp  = stat_s[tid] + djact_s[tid];
      const float hnew = fmaf(r_al, tmp, r_om * h_s[s * JS + tid]) + hn * r_ns;
      __hip_atomic_store(&hpub[(par * BB + b) * NHID + s * JS + tid], hnew,
                         __ATOMIC_RELAXED, __HIP_MEMORY_SCOPE_AGENT);
    }
    if (tid == 0) {
      asm volatile("s_waitcnt vmcnt(0)" ::: "memory");   // h-slice visible first
      __hip_atomic_store(&flags[(b * BPS + s) * FLAG_STRIDE], (uint32_t)(t + 1),
                         __ATOMIC_RELAXED, __HIP_MEMORY_SCOPE_AGENT);
    }

    // ====== P3: fold noise(t) into d -> d becomes dj(t+1) EXACTLY (hides sync) ======
    if (t + 1 < TT) {
      const uint32_t k2a = __builtin_amdgcn_readfirstlane(keys_s[t * 4 + 2]);
      const uint32_t k2b = __builtin_amdgcn_readfirstlane(keys_s[t * 4 + 3]);
      #pragma unroll
      for (int c4 = 0; c4 < 8; ++c4) {
        const uint32_t rowb = (uint32_t)(q * 32 + ((c4 + q) & 7) * 4);
        #pragma unroll
        for (int cc = 0; cc < 4; ++cc)
          d[c4*4+cc] = fmaf(bjsb, tf_normal(k2a, k2b, idx0 + ((rowb + cc) << 8)),
                            d[c4*4+cc]);
      }
      if (tid < JS) {
        const uint32_t k1a = __builtin_amdgcn_readfirstlane(keys_s[(t + 1) * 4 + 0]);
        const uint32_t k1b = __builtin_amdgcn_readfirstlane(keys_s[(t + 1) * 4 + 1]);
        hn = tf_normal(k1a, k1b, hnidx);
      }
    }

    if (wv == 0) {                       // pull full h(t+1), refresh act
      if (ln < BPS) SPIN(ln, t + 1);
      asm volatile("" ::: "memory");
      #pragma unroll
      for (int cc = 0; cc < 4; ++cc) {
        const int k = ln * 4 + cc;
        const float hv = __hip_atomic_load(&hpub[(par * BB + b) * NHID + k],
                                           __ATOMIC_RELAXED, __HIP_MEMORY_SCOPE_AGENT);
        h_s[k] = hv;
        a_s[k] = tanhf(hv);
      }
    } else if (wv == 1) {
      if (s == 0) {                      // hidden_list (single writer set)
        if (ln < BPS) SPIN(ln, t + 1);
        asm volatile("" ::: "memory");
        #pragma unroll
        for (int cc = 0; cc < 4; ++cc) {
          const int k = ln * 4 + cc;
          const float hv = __hip_atomic_load(&hpub[(par * BB + b) * NHID + k],
                                             __ATOMIC_RELAXED, __HIP_MEMORY_SCOPE_AGENT);
          out[((size_t)b * TT + t) * NHID + k] = hv;
          if (t == TT - 1)
            out[HID_LIST_SZ + OUT_LIST_SZ + (size_t)b * NHID + k] = hv;
        }
      }
    } else if (wv == 2) {
      if (t + 1 < TT) {                  // x prefetch
        xt_s[ln]      = xin[((size_t)b * TT + t + 1) * NIN + ln];
        xt_s[ln + 64] = xin[((size_t)b * TT + t + 1) * NIN + ln + 64];
      }
    }
    __syncthreads();
  }

  // ---- epilogue: output projection for t = 63 (h_s = h(64)) ----
  if (wv == 3) {
    const int o = ln >> 4, sub = ln & 15;
    float oacc = 0.0f;
    #pragma unroll
    for (int k = 0; k < 4; ++k) {
      const int col = sub * 16 + ((k + sub) & 3) * 4;
      const float4 wvv = *(const float4*)(wos + o * 260 + col);
      const float4 hv  = *(const float4*)(h_s + col);
      oacc = fmaf(wvv.x, hv.x, oacc); oacc = fmaf(wvv.y, hv.y, oacc);
      oacc = fmaf(wvv.z, hv.z, oacc); oacc = fmaf(wvv.w, hv.w, oacc);
    }
    oacc += __shfl_xor(oacc, 1); oacc += __shfl_xor(oacc, 2);
    oacc += __shfl_xor(oacc, 4); oacc += __shfl_xor(oacc, 8);
    if (sub == 0)
      out[HID_LIST_SZ + ((size_t)b * TT + (TT - 1)) * NOUT + s * 4 + o] =
          20.0f * tanhf(oacc);
  }
}

extern "C" void kernel_launch(void* const* d_in, const int* in_sizes, int n_in,
                              void* d_out, int out_size, void* d_ws, size_t ws_size,
                              hipStream_t stream) {
  (void)in_sizes; (void)n_in; (void)out_size; (void)ws_size;
  const float* x     = (const float*)d_in[0];
  const float* h0    = (const float*)d_in[1];
  // d_in[2] = length (always 64)
  const float* w_in  = (const float*)d_in[3];
  const float* w_hh  = (const float*)d_in[4];
  const float* b_hh  = (const float*)d_in[5];
  const float* w_out = (const float*)d_in[6];
  const float* alpha = (const float*)d_in[7];
  const float* beta  = (const float*)d_in[8];
  float* out = (float*)d_out;

  hipMemsetAsync((char*)d_ws + FLAG_OFF, 0, FLAG_BYTES, stream);  // flag slots
  rnn_kernel<<<dim3(NBLK), dim3(NTHR), 0, stream>>>(
      x, h0, w_in, w_hh, b_hh, w_out, alpha, beta, out, (char*)d_ws);
}

// Round 9
// 814.357 us; speedup vs baseline: 2.0151x; 1.0987x over previous
//
#include <hip/hip_runtime.h>
#include <stdint.h>

#define BB 64      // batch
#define TT 64      // time steps
#define NIN 128
#define NHID 256
#define NOUT 32
#define BPS 16                 // blocks per sample (j-sliced)
#define NBLK (BB * BPS)        // 1024 blocks = 4 per CU (guaranteed co-resident)
#define NTHR 256
#define JS 16                  // j-columns per block

#define SIG_NEU 0.05f
#define SIG_SYN 0.002f

// workspace layout (bytes)
#define FLAG_OFF    0
#define FLAG_STRIDE 32                                // u32s -> 128B per flag line
#define FLAG_BYTES  (BB * BPS * FLAG_STRIDE * 4)      // 128 KB, memset(0) per launch
#define HPUB_OFF    FLAG_BYTES                        // float[2][BB][NHID] = 128 KB

#define HID_LIST_SZ ((size_t)BB * TT * NHID)          // 1048576
#define OUT_LIST_SZ ((size_t)BB * TT * NOUT)          // 131072

__device__ __forceinline__ uint32_t rotl32(uint32_t v, int s) {
  return (v << s) | (v >> (32 - s));
}

// JAX threefry2x32 (5 groups of 4 rounds)
__device__ __forceinline__ void tf2x32(uint32_t k0, uint32_t k1, uint32_t x0, uint32_t x1,
                                       uint32_t& o0, uint32_t& o1) {
  const uint32_t k2 = k0 ^ k1 ^ 0x1BD11BDAu;
  x0 += k0; x1 += k1;
  x0 += x1; x1 = rotl32(x1,13); x1 ^= x0;
  x0 += x1; x1 = rotl32(x1,15); x1 ^= x0;
  x0 += x1; x1 = rotl32(x1,26); x1 ^= x0;
  x0 += x1; x1 = rotl32(x1, 6); x1 ^= x0;
  x0 += k1; x1 += k2 + 1u;
  x0 += x1; x1 = rotl32(x1,17); x1 ^= x0;
  x0 += x1; x1 = rotl32(x1,29); x1 ^= x0;
  x0 += x1; x1 = rotl32(x1,16); x1 ^= x0;
  x0 += x1; x1 = rotl32(x1,24); x1 ^= x0;
  x0 += k2; x1 += k0 + 2u;
  x0 += x1; x1 = rotl32(x1,13); x1 ^= x0;
  x0 += x1; x1 = rotl32(x1,15); x1 ^= x0;
  x0 += x1; x1 = rotl32(x1,26); x1 ^= x0;
  x0 += x1; x1 = rotl32(x1, 6); x1 ^= x0;
  x0 += k0; x1 += k1 + 3u;
  x0 += x1; x1 = rotl32(x1,17); x1 ^= x0;
  x0 += x1; x1 = rotl32(x1,29); x1 ^= x0;
  x0 += x1; x1 = rotl32(x1,16); x1 ^= x0;
  x0 += x1; x1 = rotl32(x1,24); x1 ^= x0;
  x0 += k1; x1 += k2 + 4u;
  x0 += x1; x1 = rotl32(x1,13); x1 ^= x0;
  x0 += x1; x1 = rotl32(x1,15); x1 ^= x0;
  x0 += x1; x1 = rotl32(x1,26); x1 ^= x0;
  x0 += x1; x1 = rotl32(x1, 6); x1 ^= x0;
  x0 += k2; x1 += k0 + 5u;
  o0 = x0; o1 = x1;
}

// partitionable random_bits(32) element idx -> N(0,1) exactly as jax.random.normal
__device__ __forceinline__ float tf_normal(uint32_t k0, uint32_t k1, uint32_t idx) {
  uint32_t o0, o1;
  tf2x32(k0, k1, 0u, idx, o0, o1);
  const uint32_t bits = o0 ^ o1;
  const float u = __uint_as_float((bits >> 9) | 0x3f800000u) - 1.0f;  // [0,1)
  float x = fmaf(u, 2.0f, -0.99999994f);                              // [-1+eps, 1)
  x = fmaxf(x, -0.99999994f);
  // XLA ErfInv f32 (Giles)
  const float w = -__logf(fmaf(-x, x, 1.0f));
  float p;
  if (w < 5.0f) {
    const float q = w - 2.5f;
    p = 2.81022636e-08f;
    p = fmaf(p, q, 3.43273939e-07f);
    p = fmaf(p, q, -3.5233877e-06f);
    p = fmaf(p, q, -4.39150654e-06f);
    p = fmaf(p, q, 0.00021858087f);
    p = fmaf(p, q, -0.00125372503f);
    p = fmaf(p, q, -0.00417768164f);
    p = fmaf(p, q, 0.246640727f);
    p = fmaf(p, q, 1.50140941f);
  } else {
    const float q = sqrtf(w) - 3.0f;
    p = -0.000200214257f;
    p = fmaf(p, q, 0.000100950558f);
    p = fmaf(p, q, 0.00134934322f);
    p = fmaf(p, q, -0.00367342844f);
    p = fmaf(p, q, 0.00573950773f);
    p = fmaf(p, q, -0.0076224613f);
    p = fmaf(p, q, 0.00943887047f);
    p = fmaf(p, q, 1.00167406f);
    p = fmaf(p, q, 2.83297682f);
  }
  return 1.41421356f * (p * x);  // sqrt(2)*erfinv
}

#define SPIN(slice, want)                                                         \
  do {                                                                            \
    uint32_t* fp_ = &flags[((b) * BPS + (slice)) * FLAG_STRIDE];                  \
    for (int it_ = 0; it_ < 2000000; ++it_) {                                     \
      if (__hip_atomic_load(fp_, __ATOMIC_RELAXED, __HIP_MEMORY_SCOPE_AGENT) >=   \
          (uint32_t)(want)) break;                                                \
      __builtin_amdgcn_s_sleep(1);                                                \
    }                                                                             \
  } while (0)

__global__ __launch_bounds__(NTHR, 4)   // 4 waves/EU min -> VGPR<=128, 4 blocks/CU guaranteed
void rnn_kernel(
    const float* __restrict__ xin, const float* __restrict__ h0,
    const float* __restrict__ w_in, const float* __restrict__ w_hh,
    const float* __restrict__ b_hh, const float* __restrict__ w_out,
    const float* __restrict__ alpha, const float* __restrict__ beta,
    float* __restrict__ out, char* __restrict__ ws)
{
  __shared__ __align__(16) float whh_s[JS * 260];   // 16.6 KB, pad 260
  __shared__ __align__(16) float win_s[JS * 132];   //  8.4 KB, pad 132
  __shared__ __align__(16) float wos[2 * 260];      //  2.1 KB
  __shared__ __align__(16) float h_s[NHID];
  __shared__ __align__(16) float a_s[NHID];
  __shared__ __align__(16) float xt_s[NIN];
  __shared__ float stat_s[JS];
  __shared__ float djact_s[JS];
  __shared__ uint32_t keys_s[TT * 4];

  const int tid = threadIdx.x;
  const int blk = blockIdx.x;
  const int b   = blk & 63;      // sample; siblings blk = s*64+b are == b (mod 8)
  const int s   = blk >> 6;      // 0..15 j-slice index

  uint32_t* flags = (uint32_t*)(ws + FLAG_OFF);
  float*    hpub  = (float*)(ws + HPUB_OFF);

  // ---------------- init ----------------
  if (tid < TT) {
    uint32_t ka, kb, t0, t1;
    tf2x32(0u, 42u, 0u, (uint32_t)tid, ka, kb);   // keys[t] = split(key(42),64)[t]
    tf2x32(ka, kb, 0u, 0u, t0, t1);               // k1 (neural)
    keys_s[tid * 4 + 0] = t0; keys_s[tid * 4 + 1] = t1;
    tf2x32(ka, kb, 0u, 1u, t0, t1);               // k2 (synaptic)
    keys_s[tid * 4 + 2] = t0; keys_s[tid * 4 + 3] = t1;
  }
  {
    const float hv = h0[b * NHID + tid];
    h_s[tid] = hv;
    a_s[tid] = tanhf(hv);
  }
  #pragma unroll
  for (int r = 0; r < JS; ++r)
    whh_s[r * 260 + tid] = w_hh[(size_t)(s * JS + r) * NHID + tid];
  {
    const int r2 = tid >> 7, c = tid & 127;
    #pragma unroll
    for (int rr = 0; rr < 8; ++rr)
      win_s[(rr * 2 + r2) * 132 + c] = w_in[(size_t)(s * JS + rr * 2 + r2) * NIN + c];
  }
  #pragma unroll
  for (int r = 0; r < 2; ++r)
    wos[r * 260 + tid] = w_out[(s * 2 + r) * NHID + tid];

  // mapping: jl = GEMV row / dj column (0..15), q = 16-lane slice (0..15)
  // thread owns dj rows i = q*16 + [0,16), rotated: d[c4*4+cc] <-> row q*16+((c4+q)&3)*4+cc
  const int q  = tid & 15;
  const int jl = tid >> 4;           // 0..15
  const int jg = s * JS + jl;        // global j (0..255)
  const float bj   = beta[jg];
  const float sbj  = SIG_SYN * sqrtf(bj);
  const float bjsb = bj * sbj;
  const uint32_t idx0 = ((uint32_t)b << 16) | (uint32_t)jg;
  const float bias = b_hh[jg];

  // h-update consts (tid<16)
  float r_al = 0.f, r_om = 0.f, r_ns = 0.f;
  uint32_t hnidx = 0;
  if (tid < JS) {
    r_al = alpha[s * JS + tid];
    r_om = 1.0f - r_al;
    r_ns = SIG_NEU * sqrtf(r_al);
    hnidx = (uint32_t)(b * NHID + s * JS + tid);
  }

  float d[16];
  #pragma unroll
  for (int r = 0; r < 16; ++r) d[r] = 0.0f;   // dj(0) = 0 EXACTLY
  float hn = 0.0f;

  __syncthreads();

  // -------- prologue: hn(0), x_0 (NO noise fold: dj(0)=0) --------
  {
    if (tid < JS) {
      const uint32_t k1a = __builtin_amdgcn_readfirstlane(keys_s[0]);
      const uint32_t k1b = __builtin_amdgcn_readfirstlane(keys_s[1]);
      hn = tf_normal(k1a, k1b, hnidx);
    }
    if (tid < NIN) xt_s[tid] = xin[((size_t)b * TT) * NIN + tid];
  }
  __syncthreads();

  const int wv = tid >> 6;     // wave id 0..3
  const int ln = tid & 63;

  for (int t = 0; t < TT; ++t) {
    const int par = t & 1;

    // ================ P1: pd + outer-update + GEMV (+outproj t-1 on wave 3) ===========
    // d == dj(t) exactly: noise(t-1) folded during the previous barrier window.
    const float aj = a_s[jg];
    float pd = 0.0f;
    float acc = 0.0f;
    #pragma unroll
    for (int c4 = 0; c4 < 4; ++c4) {
      const int col = q * 16 + ((c4 + q) & 3) * 4;               // rotated chunk
      const float4 av = *(const float4*)(a_s + col);
      const float4 wv4 = *(const float4*)(whh_s + jl * 260 + col);
      pd = fmaf(av.x, d[c4*4+0], pd);
      pd = fmaf(av.y, d[c4*4+1], pd);
      pd = fmaf(av.z, d[c4*4+2], pd);
      pd = fmaf(av.w, d[c4*4+3], pd);
      d[c4*4+0] = fmaf(bj, -av.x * aj, d[c4*4+0]);
      d[c4*4+1] = fmaf(bj, -av.y * aj, d[c4*4+1]);
      d[c4*4+2] = fmaf(bj, -av.z * aj, d[c4*4+2]);
      d[c4*4+3] = fmaf(bj, -av.w * aj, d[c4*4+3]);
      acc = fmaf(wv4.x, av.x, acc); acc = fmaf(wv4.y, av.y, acc);
      acc = fmaf(wv4.z, av.z, acc); acc = fmaf(wv4.w, av.w, acc);
    }
    #pragma unroll
    for (int k = 0; k < 2; ++k) {
      const int col = q * 8 + ((k + q) & 1) * 4;
      const float4 xv = *(const float4*)(xt_s + col);
      const float4 wv4 = *(const float4*)(win_s + jl * 132 + col);
      acc = fmaf(wv4.x, xv.x, acc); acc = fmaf(wv4.y, xv.y, acc);
      acc = fmaf(wv4.z, xv.z, acc); acc = fmaf(wv4.w, xv.w, acc);
    }
    pd  += __shfl_xor(pd, 1);  pd  += __shfl_xor(pd, 2);
    pd  += __shfl_xor(pd, 4);  pd  += __shfl_xor(pd, 8);
    acc += __shfl_xor(acc, 1); acc += __shfl_xor(acc, 2);
    acc += __shfl_xor(acc, 4); acc += __shfl_xor(acc, 8);
    if (q == 0) {
      djact_s[jl] = pd;
      stat_s[jl]  = acc + bias;
    }

    if (wv == 3 && t > 0) {   // output projection for t-1 (h_s = h(t)); 2 outputs
      const int o = ln >> 5, sub = ln & 31;
      float oacc = 0.0f;
      #pragma unroll
      for (int k = 0; k < 2; ++k) {
        const int col = sub * 8 + ((k + sub) & 1) * 4;
        const float4 wvv = *(const float4*)(wos + o * 260 + col);
        const float4 hv  = *(const float4*)(h_s + col);
        oacc = fmaf(wvv.x, hv.x, oacc); oacc = fmaf(wvv.y, hv.y, oacc);
        oacc = fmaf(wvv.z, hv.z, oacc); oacc = fmaf(wvv.w, hv.w, oacc);
      }
      oacc += __shfl_xor(oacc, 1);  oacc += __shfl_xor(oacc, 2);
      oacc += __shfl_xor(oacc, 4);  oacc += __shfl_xor(oacc, 8);
      oacc += __shfl_xor(oacc, 16);
      if (sub == 0)
        out[HID_LIST_SZ + ((size_t)b * TT + (t - 1)) * NOUT + s * 2 + o] =
            20.0f * tanhf(oacc);
    }
    __syncthreads();

    // ================ P2: h-update + publish + flag ================
    if (tid < JS) {
      const float tmp  = stat_s[tid] + djact_s[tid];
      const float hnew = fmaf(r_al, tmp, r_om * h_s[s * JS + tid]) + hn * r_ns;
      __hip_atomic_store(&hpub[(par * BB + b) * NHID + s * JS + tid], hnew,
                         __ATOMIC_RELAXED, __HIP_MEMORY_SCOPE_AGENT);
    }
    if (tid == 0) {
      asm volatile("s_waitcnt vmcnt(0)" ::: "memory");   // h-slice visible first
      __hip_atomic_store(&flags[(b * BPS + s) * FLAG_STRIDE], (uint32_t)(t + 1),
                         __ATOMIC_RELAXED, __HIP_MEMORY_SCOPE_AGENT);
    }

    // ====== P3: fold noise(t) into d -> d becomes dj(t+1) EXACTLY (hides sync) ======
    if (t + 1 < TT) {
      const uint32_t k2a = __builtin_amdgcn_readfirstlane(keys_s[t * 4 + 2]);
      const uint32_t k2b = __builtin_amdgcn_readfirstlane(keys_s[t * 4 + 3]);
      #pragma unroll
      for (int c4 = 0; c4 < 4; ++c4) {
        const uint32_t rowb = (uint32_t)(q * 16 + ((c4 + q) & 3) * 4);
        #pragma unroll
        for (int cc = 0; cc < 4; ++cc)
          d[c4*4+cc] = fmaf(bjsb, tf_normal(k2a, k2b, idx0 + ((rowb + cc) << 8)),
                            d[c4*4+cc]);
      }
      if (tid < JS) {
        const uint32_t k1a = __builtin_amdgcn_readfirstlane(keys_s[(t + 1) * 4 + 0]);
        const uint32_t k1b = __builtin_amdgcn_readfirstlane(keys_s[(t + 1) * 4 + 1]);
        hn = tf_normal(k1a, k1b, hnidx);
      }
    }

    if (wv == 0) {                       // pull full h(t+1), refresh act
      if (ln < BPS) SPIN(ln, t + 1);
      asm volatile("" ::: "memory");
      #pragma unroll
      for (int cc = 0; cc < 4; ++cc) {
        const int k = ln * 4 + cc;
        const float hv = __hip_atomic_load(&hpub[(par * BB + b) * NHID + k],
                                           __ATOMIC_RELAXED, __HIP_MEMORY_SCOPE_AGENT);
        h_s[k] = hv;
        a_s[k] = tanhf(hv);
      }
    } else if (wv == 1) {
      if (s == 0) {                      // hidden_list (single writer set)
        if (ln < BPS) SPIN(ln, t + 1);
        asm volatile("" ::: "memory");
        #pragma unroll
        for (int cc = 0; cc < 4; ++cc) {
          const int k = ln * 4 + cc;
          const float hv = __hip_atomic_load(&hpub[(par * BB + b) * NHID + k],
                                             __ATOMIC_RELAXED, __HIP_MEMORY_SCOPE_AGENT);
          out[((size_t)b * TT + t) * NHID + k] = hv;
          if (t == TT - 1)
            out[HID_LIST_SZ + OUT_LIST_SZ + (size_t)b * NHID + k] = hv;
        }
      }
    } else if (wv == 2) {
      if (t + 1 < TT) {                  // x prefetch
        xt_s[ln]      = xin[((size_t)b * TT + t + 1) * NIN + ln];
        xt_s[ln + 64] = xin[((size_t)b * TT + t + 1) * NIN + ln + 64];
      }
    }
    __syncthreads();
  }

  // ---- epilogue: output projection for t = 63 (h_s = final h) ----
  if (wv == 3) {
    const int o = ln >> 5, sub = ln & 31;
    float oacc = 0.0f;
    #pragma unroll
    for (int k = 0; k < 2; ++k) {
      const int col = sub * 8 + ((k + sub) & 1) * 4;
      const float4 wvv = *(const float4*)(wos + o * 260 + col);
      const float4 hv  = *(const float4*)(h_s + col);
      oacc = fmaf(wvv.x, hv.x, oacc); oacc = fmaf(wvv.y, hv.y, oacc);
      oacc = fmaf(wvv.z, hv.z, oacc); oacc = fmaf(wvv.w, hv.w, oacc);
    }
    oacc += __shfl_xor(oacc, 1);  oacc += __shfl_xor(oacc, 2);
    oacc += __shfl_xor(oacc, 4);  oacc += __shfl_xor(oacc, 8);
    oacc += __shfl_xor(oacc, 16);
    if (sub == 0)
      out[HID_LIST_SZ + ((size_t)b * TT + (TT - 1)) * NOUT + s * 2 + o] =
          20.0f * tanhf(oacc);
  }
}

extern "C" void kernel_launch(void* const* d_in, const int* in_sizes, int n_in,
                              void* d_out, int out_size, void* d_ws, size_t ws_size,
                              hipStream_t stream) {
  (void)in_sizes; (void)n_in; (void)out_size; (void)ws_size;
  const float* x     = (const float*)d_in[0];
  const float* h0    = (const float*)d_in[1];
  // d_in[2] = length (always 64)
  const float* w_in  = (const float*)d_in[3];
  const float* w_hh  = (const float*)d_in[4];
  const float* b_hh  = (const float*)d_in[5];
  const float* w_out = (const float*)d_in[6];
  const float* alpha = (const float*)d_in[7];
  const float* beta  = (const float*)d_in[8];
  float* out = (float*)d_out;

  hipMemsetAsync((char*)d_ws + FLAG_OFF, 0, FLAG_BYTES, stream);  // flag slots
  rnn_kernel<<<dim3(NBLK), dim3(NTHR), 0, stream>>>(
      x, h0, w_in, w_hh, b_hh, w_out, alpha, beta, out, (char*)d_ws);
}